// Round 9
// baseline (375.469 us; speedup 1.0000x reference)
//
#include <hip/hip_runtime.h>
#include <math.h>

#define TT    512
#define BB    512
#define HID   32
#define EMB   32
#define FFD   16
#define NCLS  7
#define VOCABN 1000

typedef float v2f __attribute__((ext_vector_type(2)));
typedef float v4f __attribute__((ext_vector_type(4)));

#define NLOG2E  (-1.4426950408889634f)
#define N2LOG2E (-2.8853900817779268f)

__device__ __forceinline__ float rl(float v, int k) {
    return __int_as_float(__builtin_amdgcn_readlane(__float_as_int(v), k));
}
__device__ __forceinline__ float fast_rcp(float x) {
#if defined(__has_builtin)
#if __has_builtin(__builtin_amdgcn_rcpf)
    return __builtin_amdgcn_rcpf(x);
#else
    return 1.0f / x;
#endif
#else
    return 1.0f / x;
#endif
}
__device__ __forceinline__ float sigf(float x) { return fast_rcp(1.0f + __expf(-x)); }
__device__ __forceinline__ float tanh_fast(float x) { return 2.0f * sigf(2.0f * x) - 1.0f; }

__device__ __forceinline__ v2f fma2(v2f a, v2f b, v2f c) {
#if defined(__has_builtin)
#if __has_builtin(__builtin_elementwise_fma)
    return __builtin_elementwise_fma(a, b, c);
#else
    v2f r; r.x = fmaf(a.x, b.x, c.x); r.y = fmaf(a.y, b.y, c.y); return r;
#endif
#else
    v2f r; r.x = fmaf(a.x, b.x, c.x); r.y = fmaf(a.y, b.y, c.y); return r;
#endif
}

// Cross-half (lane ^ 32) exchange via v_permlane32_swap_b32 (VALU).
// Orientation-proof: r[0]^r[1]^self == partner.
__device__ __forceinline__ float xhalf_swap(float v) {
#if defined(__has_builtin)
#if __has_builtin(__builtin_amdgcn_permlane32_swap)
    const unsigned u = __float_as_uint(v);
    auto r = __builtin_amdgcn_permlane32_swap(u, u, false, false);
    return __uint_as_float((r[0] ^ r[1]) ^ u);
#else
    return __shfl_xor(v, 32);
#endif
#else
    return __shfl_xor(v, 32);
#endif
}

// xg_table[v][j] = {W_ih[j,:]·emb[v,:]+b[j], W_ih[j+64,:]·emb[v,:]+b[j+64]}
// scaled!=0: entries pre-multiplied by activation log2-scales (see lstm_fused).
__global__ __launch_bounds__(64) void build_xg(
    const float* __restrict__ emb, const float* __restrict__ W_ih,
    const float* __restrict__ b_ih, const float* __restrict__ b_hh,
    float2* __restrict__ tab, int scaled)
{
    const int v = blockIdx.x;
    const int j = threadIdx.x;
    const float* e  = emb + v * EMB;
    const float* w0 = W_ih + j * EMB;
    const float* w1 = W_ih + (j + 64) * EMB;
    float a0 = b_ih[j]      + b_hh[j];
    float a1 = b_ih[j + 64] + b_hh[j + 64];
    #pragma unroll
    for (int k = 0; k < EMB; ++k) {
        const float ek = e[k];
        a0 = fmaf(w0[k], ek, a0);
        a1 = fmaf(w1[k], ek, a1);
    }
    float s0 = 1.0f, s1 = 1.0f;
    if (scaled) { s0 = NLOG2E; s1 = (j < 32) ? N2LOG2E : NLOG2E; }
    tab[v * 64 + j] = make_float2(a0 * s0, a1 * s1);
}

// FULLY FUSED: R5's fastest recurrence structure (689 cyc/step, 147us) with
// the FF+logits+online-softmax head folded in. R6/R7/R8 EVIDENCE: the ~500
// idle cyc/step cannot host a second recurrence chain (LDS/trans pipes double-
// pay), but R4 showed chain-INDEPENDENT instructions ride those slots for
// free. The FF head is exactly that: no LDS ops, no serial dependence; it
// consumes the h-quads the dot already read. Placed after the ds_write(h) so
// it fills the write->read broadcast latency. Deletes ff_softmax and the
// 32MB+32MB hs round trip entirely.
__global__ __launch_bounds__(64)
__attribute__((amdgpu_waves_per_eu(1, 1)))
void lstm_fused(
    const int* __restrict__ x, const float2* __restrict__ tab,
    const float* __restrict__ W_hh,
    const float* __restrict__ W1, const float* __restrict__ b1,
    const float* __restrict__ W2, const float* __restrict__ b2,
    float* __restrict__ out)
{
    const int b  = blockIdx.x;
    const int j  = threadIdx.x;
    const int m  = j & 31;
    const bool lo = j < 32;

    __shared__ __align__(16) float sh[8 * HID];

    // ---- W_hh rows j, j+64 -> 32 named v2f pairs, pre-scaled ----
    const float fA = NLOG2E;
    const float fB = lo ? N2LOG2E : NLOG2E;
    const v2f sA2 = {fA, fA};
    const v2f sB2 = {fB, fB};
    const v4f* WA = (const v4f*)(W_hh + j * HID);
    const v4f* WB = (const v4f*)(W_hh + (j + 64) * HID);
    v4f t;
    v2f wpa0,wpa1,wpa2,wpa3,wpa4,wpa5,wpa6,wpa7,wpa8,wpa9,wpa10,wpa11,wpa12,wpa13,wpa14,wpa15;
    v2f wpb0,wpb1,wpb2,wpb3,wpb4,wpb5,wpb6,wpb7,wpb8,wpb9,wpb10,wpb11,wpb12,wpb13,wpb14,wpb15;
    t = WA[0]; wpa0  = t.lo * sA2; wpa1  = t.hi * sA2;
    t = WA[1]; wpa2  = t.lo * sA2; wpa3  = t.hi * sA2;
    t = WA[2]; wpa4  = t.lo * sA2; wpa5  = t.hi * sA2;
    t = WA[3]; wpa6  = t.lo * sA2; wpa7  = t.hi * sA2;
    t = WA[4]; wpa8  = t.lo * sA2; wpa9  = t.hi * sA2;
    t = WA[5]; wpa10 = t.lo * sA2; wpa11 = t.hi * sA2;
    t = WA[6]; wpa12 = t.lo * sA2; wpa13 = t.hi * sA2;
    t = WA[7]; wpa14 = t.lo * sA2; wpa15 = t.hi * sA2;
    t = WB[0]; wpb0  = t.lo * sB2; wpb1  = t.hi * sB2;
    t = WB[1]; wpb2  = t.lo * sB2; wpb3  = t.hi * sB2;
    t = WB[2]; wpb4  = t.lo * sB2; wpb5  = t.hi * sB2;
    t = WB[3]; wpb6  = t.lo * sB2; wpb7  = t.hi * sB2;
    t = WB[4]; wpb8  = t.lo * sB2; wpb9  = t.hi * sB2;
    t = WB[5]; wpb10 = t.lo * sB2; wpb11 = t.hi * sB2;
    t = WB[6]; wpb12 = t.lo * sB2; wpb13 = t.hi * sB2;
    t = WB[7]; wpb14 = t.lo * sB2; wpb15 = t.hi * sB2;

    // ---- FF head weights: lane j handles z[f16] and class c7 ----
    const int f16 = j & 15;
    const int cls = j & 7;
    const int c7  = (cls < NCLS) ? cls : 0;
    v2f w1p0,w1p1,w1p2,w1p3,w1p4,w1p5,w1p6,w1p7,w1p8,w1p9,w1p10,w1p11,w1p12,w1p13,w1p14,w1p15;
    {
        const v4f* W1r = (const v4f*)(W1 + f16 * HID);
        v4f q;
        q = W1r[0]; w1p0  = q.lo; w1p1  = q.hi;
        q = W1r[1]; w1p2  = q.lo; w1p3  = q.hi;
        q = W1r[2]; w1p4  = q.lo; w1p5  = q.hi;
        q = W1r[3]; w1p6  = q.lo; w1p7  = q.hi;
        q = W1r[4]; w1p8  = q.lo; w1p9  = q.hi;
        q = W1r[5]; w1p10 = q.lo; w1p11 = q.hi;
        q = W1r[6]; w1p12 = q.lo; w1p13 = q.hi;
        q = W1r[7]; w1p14 = q.lo; w1p15 = q.hi;
    }
    float w2r[FFD];
    #pragma unroll
    for (int f = 0; f < FFD; ++f) w2r[f] = W2[c7 * FFD + f];
    const float b1v = b1[f16];
    const float b2v = b2[c7];

    float h = 0.f, c = 0.f;
    float mrun = -3.0e38f, srun = 0.f;

    // FF head for step t_out, consuming the broadcast quads of h_{t_out}
    auto ff_head = [&](int t_out, v4f h0, v4f h1, v4f h2, v4f h3,
                                  v4f h4, v4f h5, v4f h6, v4f h7) {
        v2f z0 = {b1v, 0.f}, z1 = {0.f, 0.f};
        z0 = fma2(w1p0,  h0.lo, z0);  z1 = fma2(w1p1,  h0.hi, z1);
        z0 = fma2(w1p2,  h1.lo, z0);  z1 = fma2(w1p3,  h1.hi, z1);
        z0 = fma2(w1p4,  h2.lo, z0);  z1 = fma2(w1p5,  h2.hi, z1);
        z0 = fma2(w1p6,  h3.lo, z0);  z1 = fma2(w1p7,  h3.hi, z1);
        z0 = fma2(w1p8,  h4.lo, z0);  z1 = fma2(w1p9,  h4.hi, z1);
        z0 = fma2(w1p10, h5.lo, z0);  z1 = fma2(w1p11, h5.hi, z1);
        z0 = fma2(w1p12, h6.lo, z0);  z1 = fma2(w1p13, h6.hi, z1);
        z0 = fma2(w1p14, h7.lo, z0);  z1 = fma2(w1p15, h7.hi, z1);
        const v2f zs = z0 + z1;
        const float z = fmaxf(zs.x + zs.y, 0.0f);
        float lgv = b2v;
        #pragma unroll
        for (int f = 0; f < FFD; ++f) lgv = fmaf(w2r[f], rl(z, f), lgv);
        const float mn = fmaxf(mrun, lgv);
        srun = fmaf(srun, __expf(mrun - mn), __expf(lgv - mn));
        mrun = mn;
        if (j < NCLS) out[((size_t)t_out * BB + b) * NCLS + j] = lgv;
    };

    // broadcast source slot 7 = "previous h"; zero for t=0
    if (lo) sh[7 * HID + m] = 0.0f;

    // ---- prologue: block-0 xg in registers, block-1 indices staged ----
    int xiB[8];
    float2 cxg[8];
    {
        int xi0[8];
        #pragma unroll
        for (int u = 0; u < 8; ++u) xi0[u] = x[u * BB + b];
        #pragma unroll
        for (int u = 0; u < 8; ++u) xiB[u] = x[(8 + u) * BB + b];
        #pragma unroll
        for (int u = 0; u < 8; ++u) cxg[u] = tab[(size_t)xi0[u] * 64 + j];
    }

    for (int t8 = 0; t8 < TT / 8; ++t8) {
        // next-block gathers + next-next-block index loads up front;
        // consumed after the 8 serial steps below -> latency fully hidden.
        float2 nxg[8];
        #pragma unroll
        for (int u = 0; u < 8; ++u) nxg[u] = tab[(size_t)xiB[u] * 64 + j];
        int xiN[8];
        const int nb2 = (t8 + 2 < TT / 8) ? (t8 + 2) * 8 : 0;  // tail: dead but safe
        #pragma unroll
        for (int u = 0; u < 8; ++u) xiN[u] = x[(nb2 + u) * BB + b];

        #pragma unroll
        for (int u = 0; u < 8; ++u) {
            // broadcast: previous step's h lives in sh slot (u-1)&7.
            // Uniform-address ds_read_b128 -> all lanes get the same quad.
            const float* hb = sh + ((u + 7) & 7) * HID;
            const v4f h0 = *(const v4f*)(hb + 0);
            const v4f h1 = *(const v4f*)(hb + 4);
            const v4f h2 = *(const v4f*)(hb + 8);
            const v4f h3 = *(const v4f*)(hb + 12);
            const v4f h4 = *(const v4f*)(hb + 16);
            const v4f h5 = *(const v4f*)(hb + 20);
            const v4f h6 = *(const v4f*)(hb + 24);
            const v4f h7 = *(const v4f*)(hb + 28);

            // dot: 32 pk_fma in 4 independent chains of depth 8
            v2f aP0 = {cxg[u].x, 0.f}, aP1 = {0.f, 0.f};
            v2f aQ0 = {cxg[u].y, 0.f}, aQ1 = {0.f, 0.f};
            aP0 = fma2(wpa0,  h0.lo, aP0);  aP1 = fma2(wpa1,  h0.hi, aP1);
            aQ0 = fma2(wpb0,  h0.lo, aQ0);  aQ1 = fma2(wpb1,  h0.hi, aQ1);
            aP0 = fma2(wpa2,  h1.lo, aP0);  aP1 = fma2(wpa3,  h1.hi, aP1);
            aQ0 = fma2(wpb2,  h1.lo, aQ0);  aQ1 = fma2(wpb3,  h1.hi, aQ1);
            aP0 = fma2(wpa4,  h2.lo, aP0);  aP1 = fma2(wpa5,  h2.hi, aP1);
            aQ0 = fma2(wpb4,  h2.lo, aQ0);  aQ1 = fma2(wpb5,  h2.hi, aQ1);
            aP0 = fma2(wpa6,  h3.lo, aP0);  aP1 = fma2(wpa7,  h3.hi, aP1);
            aQ0 = fma2(wpb6,  h3.lo, aQ0);  aQ1 = fma2(wpb7,  h3.hi, aQ1);
            aP0 = fma2(wpa8,  h4.lo, aP0);  aP1 = fma2(wpa9,  h4.hi, aP1);
            aQ0 = fma2(wpb8,  h4.lo, aQ0);  aQ1 = fma2(wpb9,  h4.hi, aQ1);
            aP0 = fma2(wpa10, h5.lo, aP0);  aP1 = fma2(wpa11, h5.hi, aP1);
            aQ0 = fma2(wpb10, h5.lo, aQ0);  aQ1 = fma2(wpb11, h5.hi, aQ1);
            aP0 = fma2(wpa12, h6.lo, aP0);  aP1 = fma2(wpa13, h6.hi, aP1);
            aQ0 = fma2(wpb12, h6.lo, aQ0);  aQ1 = fma2(wpb13, h6.hi, aQ1);
            aP0 = fma2(wpa14, h7.lo, aP0);  aP1 = fma2(wpa15, h7.hi, aP1);
            aQ0 = fma2(wpb14, h7.lo, aQ0);  aQ1 = fma2(wpb15, h7.hi, aQ1);
            const v2f aP = aP0 + aP1;
            const v2f aQ = aQ0 + aQ1;
            const float accA = aP.x + aP.y;   // pre-scaled by -log2e
            const float accB = aQ.x + aQ.y;   // pre-scaled (-2log2e g / -log2e o)

            // sigmoid/tanh in exp2 form (scales folded into acc)
            const float actA = fast_rcp(1.0f + __builtin_exp2f(accA)); // i (lo) / f (hi)
            const float sgB  = fast_rcp(1.0f + __builtin_exp2f(accB));
            const float actB = lo ? fmaf(2.0f, sgB, -1.0f) : sgB;      // g (lo) / o (hi)
            const float oA = xhalf_swap(actA);
            const float oB = xhalf_swap(actB);
            const float gi = lo ? actA : oA;
            const float gf = lo ? oA   : actA;
            const float gg = lo ? actB : oB;
            const float go = lo ? oB   : actB;
            c = fmaf(gf, c, gi * gg);
            const float tc = fmaf(2.0f,
                fast_rcp(1.0f + __builtin_exp2f(c * N2LOG2E)), -1.0f); // tanh(c)
            h = go * tc;

            if (lo) sh[u * HID + m] = h;   // staging write == next-step broadcast src

            // FF head for t-1 (independent of the recurrence chain; fills the
            // ds_write->ds_read broadcast latency). Skip the nonexistent t=-1.
            if (t8 + u > 0)
                ff_head(t8 * 8 + u - 1, h0, h1, h2, h3, h4, h5, h6, h7);
        }

        // rotate double buffers
        #pragma unroll
        for (int u = 0; u < 8; ++u) { cxg[u] = nxg[u]; xiB[u] = xiN[u]; }
    }

    // final FF head for t = TT-1 (h_511 sits in slot 7)
    {
        const float* hb = sh + 7 * HID;
        const v4f h0 = *(const v4f*)(hb + 0);
        const v4f h1 = *(const v4f*)(hb + 4);
        const v4f h2 = *(const v4f*)(hb + 8);
        const v4f h3 = *(const v4f*)(hb + 12);
        const v4f h4 = *(const v4f*)(hb + 16);
        const v4f h5 = *(const v4f*)(hb + 20);
        const v4f h6 = *(const v4f*)(hb + 24);
        const v4f h7 = *(const v4f*)(hb + 28);
        ff_head(TT - 1, h0, h1, h2, h3, h4, h5, h6, h7);
    }

    // softmax-over-t normalization (verified pattern from lstm_all)
    #pragma unroll 1
    for (int cc = 0; cc < NCLS; ++cc) {
        const float mc = rl(mrun, cc);
        const float sc = rl(srun, cc);
        const float ic = 1.0f / sc;
        #pragma unroll
        for (int i = 0; i < TT / 64; ++i) {
            const int tt = j + 64 * i;
            const int a = (tt * BB + b) * NCLS + cc;
            out[a] = __expf(out[a] - mc) * ic;
        }
    }
}

// ---------------- round-2 verified fused kernel (fallback path) ----------------
template <bool TAB>
__global__ __launch_bounds__(64) void lstm_all(
    const int* __restrict__ x, const float* __restrict__ emb,
    const float* __restrict__ W_ih, const float* __restrict__ W_hh,
    const float* __restrict__ b_ih, const float* __restrict__ b_hh,
    const float* __restrict__ W1, const float* __restrict__ b1,
    const float* __restrict__ W2, const float* __restrict__ b2,
    const float2* __restrict__ tab, float* __restrict__ out)
{
    const int b  = blockIdx.x;
    const int j  = threadIdx.x;
    const int m  = j & 31;
    const bool lo = j < 32;
    const int rA = j, rB = j + 64;

    float whhA[HID], whhB[HID];
    #pragma unroll
    for (int k = 0; k < HID; k += 4) {
        float4 a;
        a = *(const float4*)(W_hh + rA * HID + k); whhA[k]=a.x; whhA[k+1]=a.y; whhA[k+2]=a.z; whhA[k+3]=a.w;
        a = *(const float4*)(W_hh + rB * HID + k); whhB[k]=a.x; whhB[k+1]=a.y; whhB[k+2]=a.z; whhB[k+3]=a.w;
    }
    float wihA[HID], wihB[HID];
    float biasA = 0.f, biasB = 0.f;
    if constexpr (!TAB) {
        #pragma unroll
        for (int k = 0; k < HID; k += 4) {
            float4 a;
            a = *(const float4*)(W_ih + rA * HID + k); wihA[k]=a.x; wihA[k+1]=a.y; wihA[k+2]=a.z; wihA[k+3]=a.w;
            a = *(const float4*)(W_ih + rB * HID + k); wihB[k]=a.x; wihB[k+1]=a.y; wihB[k+2]=a.z; wihB[k+3]=a.w;
        }
        biasA = b_ih[rA] + b_hh[rA];
        biasB = b_ih[rB] + b_hh[rB];
    }
    const int f16 = j & 15;
    float w1r[HID];
    #pragma unroll
    for (int k = 0; k < HID; ++k) w1r[k] = W1[f16 * HID + k];
    const int cls = j & 7;
    const int c7  = (cls < NCLS) ? cls : 0;
    float w2r[FFD];
    #pragma unroll
    for (int f = 0; f < FFD; ++f) w2r[f] = W2[c7 * FFD + f];
    const float b1v = b1[f16];
    const float b2v = b2[c7];

    float h = 0.f, c = 0.f;
    float mrun = -3.0e38f, srun = 0.f;

    auto gates = [&](float accA, float accB) {
        const float actA = sigf(accA);
        const float sB   = lo ? 2.0f * accB : accB;
        const float sgB  = sigf(sB);
        const float actB = lo ? 2.0f * sgB - 1.0f : sgB;
        const float oA = __shfl_xor(actA, 32);
        const float oB = __shfl_xor(actB, 32);
        const float gi = lo ? actA : oA;
        const float gf = lo ? oA   : actA;
        const float gg = lo ? actB : oB;
        const float go = lo ? oB   : actB;
        c = fmaf(gf, c, gi * gg);
        h = go * tanh_fast(c);
    };

    auto ff_head = [&](int t_out, const float* hsv) {
        float z0 = b1v, z1 = 0.f;
        #pragma unroll
        for (int k = 0; k < HID; k += 2) {
            z0 = fmaf(w1r[k],     hsv[k],     z0);
            z1 = fmaf(w1r[k + 1], hsv[k + 1], z1);
        }
        const float z = fmaxf(z0 + z1, 0.0f);
        float lgv = b2v;
        #pragma unroll
        for (int f = 0; f < FFD; ++f) lgv = fmaf(w2r[f], rl(z, f), lgv);
        const float mn = fmaxf(mrun, lgv);
        srun = fmaf(srun, __expf(mrun - mn), __expf(lgv - mn));
        mrun = mn;
        if (j < NCLS) out[(t_out * BB + b) * NCLS + j] = lgv;
    };

    int xvn1 = x[1 * BB + b];
    int xvn2 = x[2 * BB + b];
    float2 xg = make_float2(0.f, 0.f);
    float eA = 0.f;
    if constexpr (TAB) xg = tab[(size_t)x[b] * 64 + j];
    else               eA = emb[x[b] * EMB + m];

    if constexpr (TAB) {
        gates(xg.x, xg.y);
    } else {
        float es[EMB];
        #pragma unroll
        for (int k = 0; k < EMB; ++k) es[k] = rl(eA, k);
        float p0 = biasA, p1 = 0.f, q0 = biasB, q1 = 0.f;
        #pragma unroll
        for (int k = 0; k < EMB; k += 2) {
            p0 = fmaf(wihA[k],   es[k],   p0); p1 = fmaf(wihA[k+1], es[k+1], p1);
            q0 = fmaf(wihB[k],   es[k],   q0); q1 = fmaf(wihB[k+1], es[k+1], q1);
        }
        gates(p0 + p1, q0 + q1);
    }
    if constexpr (TAB) xg = tab[(size_t)xvn1 * 64 + j];
    else               eA = emb[xvn1 * EMB + m];
    xvn1 = xvn2;
    xvn2 = x[3 * BB + b];

    for (int t = 1; t < TT; ++t) {
        float2 xg_n = make_float2(0.f, 0.f);
        float  e_n  = 0.f;
        if (t + 1 < TT) {
            if constexpr (TAB) xg_n = tab[(size_t)xvn1 * 64 + j];
            else               e_n  = emb[xvn1 * EMB + m];
        }
        const int xv_n3 = (t + 3 < TT) ? x[(t + 3) * BB + b] : 0;

        float hsv[HID];
        #pragma unroll
        for (int k = 0; k < HID; ++k) hsv[k] = rl(h, k);

        ff_head(t - 1, hsv);

        float p0, p1 = 0.f, q0, q1 = 0.f;
        if constexpr (TAB) { p0 = xg.x; q0 = xg.y; }
        else               { p0 = biasA; q0 = biasB; }
        if constexpr (!TAB) {
            float es[EMB];
            #pragma unroll
            for (int k = 0; k < EMB; ++k) es[k] = rl(eA, k);
            #pragma unroll
            for (int k = 0; k < EMB; k += 2) {
                p0 = fmaf(wihA[k],   es[k],   p0); p1 = fmaf(wihA[k+1], es[k+1], p1);
                q0 = fmaf(wihB[k],   es[k],   q0); q1 = fmaf(wihB[k+1], es[k+1], q1);
            }
        }
        #pragma unroll
        for (int k = 0; k < HID; k += 2) {
            p0 = fmaf(whhA[k],   hsv[k],   p0); p1 = fmaf(whhA[k+1], hsv[k+1], p1);
            q0 = fmaf(whhB[k],   hsv[k],   q0); q1 = fmaf(whhB[k+1], hsv[k+1], q1);
        }
        gates(p0 + p1, q0 + q1);

        xg = xg_n; eA = e_n; xvn1 = xvn2; xvn2 = xv_n3;
    }

    {
        float hsv[HID];
        #pragma unroll
        for (int k = 0; k < HID; ++k) hsv[k] = rl(h, k);
        ff_head(TT - 1, hsv);
    }

    #pragma unroll 1
    for (int cc = 0; cc < NCLS; ++cc) {
        const float mc = rl(mrun, cc);
        const float sc = rl(srun, cc);
        const float ic = 1.0f / sc;
        #pragma unroll
        for (int i = 0; i < TT / 64; ++i) {
            const int t = j + 64 * i;
            const int a = (t * BB + b) * NCLS + cc;
            out[a] = __expf(out[a] - mc) * ic;
        }
    }
}

extern "C" void kernel_launch(void* const* d_in, const int* in_sizes, int n_in,
                              void* d_out, int out_size, void* d_ws, size_t ws_size,
                              hipStream_t stream) {
    const int*   x   = (const int*)  d_in[0];
    const float* emb = (const float*)d_in[1];
    const float* Wih = (const float*)d_in[2];
    const float* Whh = (const float*)d_in[3];
    const float* bih = (const float*)d_in[4];
    const float* bhh = (const float*)d_in[5];
    const float* W1  = (const float*)d_in[6];
    const float* b1  = (const float*)d_in[7];
    const float* W2  = (const float*)d_in[8];
    const float* b2  = (const float*)d_in[9];
    float* out = (float*)d_out;

    const size_t tab_bytes = (size_t)VOCABN * 128 * sizeof(float);   // 512 000
    if (ws_size >= tab_bytes) {
        float2* tab = (float2*)d_ws;
        build_xg<<<VOCABN, 64, 0, stream>>>(emb, Wih, bih, bhh, tab, 1);
        lstm_fused<<<BB, 64, 0, stream>>>(x, tab, Whh, W1, b1, W2, b2, out);
    } else {
        lstm_all<false><<<BB, 64, 0, stream>>>(x, emb, Wih, Whh, bih, bhh,
                                               W1, b1, W2, b2, nullptr, out);
    }
}

// Round 10
// 301.701 us; speedup vs baseline: 1.2445x; 1.2445x over previous
//
#include <hip/hip_runtime.h>
#include <math.h>

#define TT    512
#define BB    512
#define HID   32
#define EMB   32
#define FFD   16
#define NCLS  7
#define VOCABN 1000

typedef float v2f __attribute__((ext_vector_type(2)));
typedef float v4f __attribute__((ext_vector_type(4)));

#define NLOG2E  (-1.4426950408889634f)
#define N2LOG2E (-2.8853900817779268f)

__device__ __forceinline__ float rl(float v, int k) {
    return __int_as_float(__builtin_amdgcn_readlane(__float_as_int(v), k));
}
__device__ __forceinline__ float fast_rcp(float x) {
#if defined(__has_builtin)
#if __has_builtin(__builtin_amdgcn_rcpf)
    return __builtin_amdgcn_rcpf(x);
#else
    return 1.0f / x;
#endif
#else
    return 1.0f / x;
#endif
}
__device__ __forceinline__ float sigf(float x) { return fast_rcp(1.0f + __expf(-x)); }
__device__ __forceinline__ float tanh_fast(float x) { return 2.0f * sigf(2.0f * x) - 1.0f; }

__device__ __forceinline__ v2f fma2(v2f a, v2f b, v2f c) {
#if defined(__has_builtin)
#if __has_builtin(__builtin_elementwise_fma)
    return __builtin_elementwise_fma(a, b, c);
#else
    v2f r; r.x = fmaf(a.x, b.x, c.x); r.y = fmaf(a.y, b.y, c.y); return r;
#endif
#else
    v2f r; r.x = fmaf(a.x, b.x, c.x); r.y = fmaf(a.y, b.y, c.y); return r;
#endif
}

// Cross-half (lane ^ 32) exchange via v_permlane32_swap_b32 (VALU).
// Orientation-proof: r[0]^r[1]^self == partner.
__device__ __forceinline__ float xhalf_swap(float v) {
#if defined(__has_builtin)
#if __has_builtin(__builtin_amdgcn_permlane32_swap)
    const unsigned u = __float_as_uint(v);
    auto r = __builtin_amdgcn_permlane32_swap(u, u, false, false);
    return __uint_as_float((r[0] ^ r[1]) ^ u);
#else
    return __shfl_xor(v, 32);
#endif
#else
    return __shfl_xor(v, 32);
#endif
}

// xg_table[v][j] = {W_ih[j,:]·emb[v,:]+b[j], W_ih[j+64,:]·emb[v,:]+b[j+64]}
// scaled!=0: entries pre-multiplied by activation log2-scales (see lstm_fused).
__global__ __launch_bounds__(64) void build_xg(
    const float* __restrict__ emb, const float* __restrict__ W_ih,
    const float* __restrict__ b_ih, const float* __restrict__ b_hh,
    float2* __restrict__ tab, int scaled)
{
    const int v = blockIdx.x;
    const int j = threadIdx.x;
    const float* e  = emb + v * EMB;
    const float* w0 = W_ih + j * EMB;
    const float* w1 = W_ih + (j + 64) * EMB;
    float a0 = b_ih[j]      + b_hh[j];
    float a1 = b_ih[j + 64] + b_hh[j + 64];
    #pragma unroll
    for (int k = 0; k < EMB; ++k) {
        const float ek = e[k];
        a0 = fmaf(w0[k], ek, a0);
        a1 = fmaf(w1[k], ek, a1);
    }
    float s0 = 1.0f, s1 = 1.0f;
    if (scaled) { s0 = NLOG2E; s1 = (j < 32) ? N2LOG2E : NLOG2E; }
    tab[v * 64 + j] = make_float2(a0 * s0, a1 * s1);
}

// FULLY FUSED, LDS-staged logits. R9 EVIDENCE: the fused compute structure is
// correct and the FF work rides the stall slots, but staging logits through
// GLOBAL was catastrophic (FETCH 117MB / WRITE 75MB: per-step 28B scattered
// write-allocate RMW + epilogue global re-read + 7-pass line rewrite).
// THIS version stages logits in LDS (shlg[512][8] = 16KB, lanes 0-6 write 7
// consecutive banks, conflict-free, fire-and-forget) and the epilogue writes
// out ONCE, t-outer, 28B contiguous per row. Loop does zero global stores.
__global__ __launch_bounds__(64)
__attribute__((amdgpu_waves_per_eu(1, 1)))
void lstm_fused(
    const int* __restrict__ x, const float2* __restrict__ tab,
    const float* __restrict__ W_hh,
    const float* __restrict__ W1, const float* __restrict__ b1,
    const float* __restrict__ W2, const float* __restrict__ b2,
    float* __restrict__ out)
{
    const int b  = blockIdx.x;
    const int j  = threadIdx.x;
    const int m  = j & 31;
    const bool lo = j < 32;

    __shared__ __align__(16) float sh[8 * HID];     // h broadcast staging (1 KB)
    __shared__ __align__(32) float shlg[TT][8];     // logits [t][cls] (16 KB)

    // ---- W_hh rows j, j+64 -> 32 named v2f pairs, pre-scaled ----
    const float fA = NLOG2E;
    const float fB = lo ? N2LOG2E : NLOG2E;
    const v2f sA2 = {fA, fA};
    const v2f sB2 = {fB, fB};
    const v4f* WA = (const v4f*)(W_hh + j * HID);
    const v4f* WB = (const v4f*)(W_hh + (j + 64) * HID);
    v4f t;
    v2f wpa0,wpa1,wpa2,wpa3,wpa4,wpa5,wpa6,wpa7,wpa8,wpa9,wpa10,wpa11,wpa12,wpa13,wpa14,wpa15;
    v2f wpb0,wpb1,wpb2,wpb3,wpb4,wpb5,wpb6,wpb7,wpb8,wpb9,wpb10,wpb11,wpb12,wpb13,wpb14,wpb15;
    t = WA[0]; wpa0  = t.lo * sA2; wpa1  = t.hi * sA2;
    t = WA[1]; wpa2  = t.lo * sA2; wpa3  = t.hi * sA2;
    t = WA[2]; wpa4  = t.lo * sA2; wpa5  = t.hi * sA2;
    t = WA[3]; wpa6  = t.lo * sA2; wpa7  = t.hi * sA2;
    t = WA[4]; wpa8  = t.lo * sA2; wpa9  = t.hi * sA2;
    t = WA[5]; wpa10 = t.lo * sA2; wpa11 = t.hi * sA2;
    t = WA[6]; wpa12 = t.lo * sA2; wpa13 = t.hi * sA2;
    t = WA[7]; wpa14 = t.lo * sA2; wpa15 = t.hi * sA2;
    t = WB[0]; wpb0  = t.lo * sB2; wpb1  = t.hi * sB2;
    t = WB[1]; wpb2  = t.lo * sB2; wpb3  = t.hi * sB2;
    t = WB[2]; wpb4  = t.lo * sB2; wpb5  = t.hi * sB2;
    t = WB[3]; wpb6  = t.lo * sB2; wpb7  = t.hi * sB2;
    t = WB[4]; wpb8  = t.lo * sB2; wpb9  = t.hi * sB2;
    t = WB[5]; wpb10 = t.lo * sB2; wpb11 = t.hi * sB2;
    t = WB[6]; wpb12 = t.lo * sB2; wpb13 = t.hi * sB2;
    t = WB[7]; wpb14 = t.lo * sB2; wpb15 = t.hi * sB2;

    // ---- FF head weights: lane j handles z[f16] and class c7 ----
    const int f16 = j & 15;
    const int cls = j & 7;
    const int c7  = (cls < NCLS) ? cls : 0;
    v2f w1p0,w1p1,w1p2,w1p3,w1p4,w1p5,w1p6,w1p7,w1p8,w1p9,w1p10,w1p11,w1p12,w1p13,w1p14,w1p15;
    {
        const v4f* W1r = (const v4f*)(W1 + f16 * HID);
        v4f q;
        q = W1r[0]; w1p0  = q.lo; w1p1  = q.hi;
        q = W1r[1]; w1p2  = q.lo; w1p3  = q.hi;
        q = W1r[2]; w1p4  = q.lo; w1p5  = q.hi;
        q = W1r[3]; w1p6  = q.lo; w1p7  = q.hi;
        q = W1r[4]; w1p8  = q.lo; w1p9  = q.hi;
        q = W1r[5]; w1p10 = q.lo; w1p11 = q.hi;
        q = W1r[6]; w1p12 = q.lo; w1p13 = q.hi;
        q = W1r[7]; w1p14 = q.lo; w1p15 = q.hi;
    }
    float w2r[FFD];
    #pragma unroll
    for (int f = 0; f < FFD; ++f) w2r[f] = W2[c7 * FFD + f];
    const float b1v = b1[f16];
    const float b2v = b2[c7];

    float h = 0.f, c = 0.f;
    float mrun = -3.0e38f, srun = 0.f;

    // FF head for step t_out, consuming the broadcast quads of h_{t_out}.
    // Logit goes to LDS (conflict-free 7-bank write), NOT global.
    auto ff_head = [&](int t_out, v4f h0, v4f h1, v4f h2, v4f h3,
                                  v4f h4, v4f h5, v4f h6, v4f h7) {
        v2f z0 = {b1v, 0.f}, z1 = {0.f, 0.f};
        z0 = fma2(w1p0,  h0.lo, z0);  z1 = fma2(w1p1,  h0.hi, z1);
        z0 = fma2(w1p2,  h1.lo, z0);  z1 = fma2(w1p3,  h1.hi, z1);
        z0 = fma2(w1p4,  h2.lo, z0);  z1 = fma2(w1p5,  h2.hi, z1);
        z0 = fma2(w1p6,  h3.lo, z0);  z1 = fma2(w1p7,  h3.hi, z1);
        z0 = fma2(w1p8,  h4.lo, z0);  z1 = fma2(w1p9,  h4.hi, z1);
        z0 = fma2(w1p10, h5.lo, z0);  z1 = fma2(w1p11, h5.hi, z1);
        z0 = fma2(w1p12, h6.lo, z0);  z1 = fma2(w1p13, h6.hi, z1);
        z0 = fma2(w1p14, h7.lo, z0);  z1 = fma2(w1p15, h7.hi, z1);
        const v2f zs = z0 + z1;
        const float z = fmaxf(zs.x + zs.y, 0.0f);
        float lgv = b2v;
        #pragma unroll
        for (int f = 0; f < FFD; ++f) lgv = fmaf(w2r[f], rl(z, f), lgv);
        const float mn = fmaxf(mrun, lgv);
        srun = fmaf(srun, __expf(mrun - mn), __expf(lgv - mn));
        mrun = mn;
        if (j < NCLS) shlg[t_out][j] = lgv;
    };

    // broadcast source slot 7 = "previous h"; zero for t=0
    if (lo) sh[7 * HID + m] = 0.0f;

    // ---- prologue: block-0 xg in registers, block-1 indices staged ----
    int xiB[8];
    float2 cxg[8];
    {
        int xi0[8];
        #pragma unroll
        for (int u = 0; u < 8; ++u) xi0[u] = x[u * BB + b];
        #pragma unroll
        for (int u = 0; u < 8; ++u) xiB[u] = x[(8 + u) * BB + b];
        #pragma unroll
        for (int u = 0; u < 8; ++u) cxg[u] = tab[(size_t)xi0[u] * 64 + j];
    }

    for (int t8 = 0; t8 < TT / 8; ++t8) {
        // next-block gathers + next-next-block index loads up front;
        // consumed after the 8 serial steps below -> latency fully hidden.
        float2 nxg[8];
        #pragma unroll
        for (int u = 0; u < 8; ++u) nxg[u] = tab[(size_t)xiB[u] * 64 + j];
        int xiN[8];
        const int nb2 = (t8 + 2 < TT / 8) ? (t8 + 2) * 8 : 0;  // tail: dead but safe
        #pragma unroll
        for (int u = 0; u < 8; ++u) xiN[u] = x[(nb2 + u) * BB + b];

        #pragma unroll
        for (int u = 0; u < 8; ++u) {
            // broadcast: previous step's h lives in sh slot (u-1)&7.
            // Uniform-address ds_read_b128 -> all lanes get the same quad.
            const float* hb = sh + ((u + 7) & 7) * HID;
            const v4f h0 = *(const v4f*)(hb + 0);
            const v4f h1 = *(const v4f*)(hb + 4);
            const v4f h2 = *(const v4f*)(hb + 8);
            const v4f h3 = *(const v4f*)(hb + 12);
            const v4f h4 = *(const v4f*)(hb + 16);
            const v4f h5 = *(const v4f*)(hb + 20);
            const v4f h6 = *(const v4f*)(hb + 24);
            const v4f h7 = *(const v4f*)(hb + 28);

            // dot: 32 pk_fma in 4 independent chains of depth 8
            v2f aP0 = {cxg[u].x, 0.f}, aP1 = {0.f, 0.f};
            v2f aQ0 = {cxg[u].y, 0.f}, aQ1 = {0.f, 0.f};
            aP0 = fma2(wpa0,  h0.lo, aP0);  aP1 = fma2(wpa1,  h0.hi, aP1);
            aQ0 = fma2(wpb0,  h0.lo, aQ0);  aQ1 = fma2(wpb1,  h0.hi, aQ1);
            aP0 = fma2(wpa2,  h1.lo, aP0);  aP1 = fma2(wpa3,  h1.hi, aP1);
            aQ0 = fma2(wpb2,  h1.lo, aQ0);  aQ1 = fma2(wpb3,  h1.hi, aQ1);
            aP0 = fma2(wpa4,  h2.lo, aP0);  aP1 = fma2(wpa5,  h2.hi, aP1);
            aQ0 = fma2(wpb4,  h2.lo, aQ0);  aQ1 = fma2(wpb5,  h2.hi, aQ1);
            aP0 = fma2(wpa6,  h3.lo, aP0);  aP1 = fma2(wpa7,  h3.hi, aP1);
            aQ0 = fma2(wpb6,  h3.lo, aQ0);  aQ1 = fma2(wpb7,  h3.hi, aQ1);
            aP0 = fma2(wpa8,  h4.lo, aP0);  aP1 = fma2(wpa9,  h4.hi, aP1);
            aQ0 = fma2(wpb8,  h4.lo, aQ0);  aQ1 = fma2(wpb9,  h4.hi, aQ1);
            aP0 = fma2(wpa10, h5.lo, aP0);  aP1 = fma2(wpa11, h5.hi, aP1);
            aQ0 = fma2(wpb10, h5.lo, aQ0);  aQ1 = fma2(wpb11, h5.hi, aQ1);
            aP0 = fma2(wpa12, h6.lo, aP0);  aP1 = fma2(wpa13, h6.hi, aP1);
            aQ0 = fma2(wpb12, h6.lo, aQ0);  aQ1 = fma2(wpb13, h6.hi, aQ1);
            aP0 = fma2(wpa14, h7.lo, aP0);  aP1 = fma2(wpa15, h7.hi, aP1);
            aQ0 = fma2(wpb14, h7.lo, aQ0);  aQ1 = fma2(wpb15, h7.hi, aQ1);
            const v2f aP = aP0 + aP1;
            const v2f aQ = aQ0 + aQ1;
            const float accA = aP.x + aP.y;   // pre-scaled by -log2e
            const float accB = aQ.x + aQ.y;   // pre-scaled (-2log2e g / -log2e o)

            // sigmoid/tanh in exp2 form (scales folded into acc)
            const float actA = fast_rcp(1.0f + __builtin_exp2f(accA)); // i (lo) / f (hi)
            const float sgB  = fast_rcp(1.0f + __builtin_exp2f(accB));
            const float actB = lo ? fmaf(2.0f, sgB, -1.0f) : sgB;      // g (lo) / o (hi)
            const float oA = xhalf_swap(actA);
            const float oB = xhalf_swap(actB);
            const float gi = lo ? actA : oA;
            const float gf = lo ? oA   : actA;
            const float gg = lo ? actB : oB;
            const float go = lo ? oB   : actB;
            c = fmaf(gf, c, gi * gg);
            const float tc = fmaf(2.0f,
                fast_rcp(1.0f + __builtin_exp2f(c * N2LOG2E)), -1.0f); // tanh(c)
            h = go * tc;

            if (lo) sh[u * HID + m] = h;   // staging write == next-step broadcast src

            // FF head for t-1 (independent of the recurrence chain; fills the
            // ds_write->ds_read broadcast latency). Skip the nonexistent t=-1.
            if (t8 + u > 0)
                ff_head(t8 * 8 + u - 1, h0, h1, h2, h3, h4, h5, h6, h7);
        }

        // rotate double buffers
        #pragma unroll
        for (int u = 0; u < 8; ++u) { cxg[u] = nxg[u]; xiB[u] = xiN[u]; }
    }

    // final FF head for t = TT-1 (h_511 sits in slot 7)
    {
        const float* hb = sh + 7 * HID;
        const v4f h0 = *(const v4f*)(hb + 0);
        const v4f h1 = *(const v4f*)(hb + 4);
        const v4f h2 = *(const v4f*)(hb + 8);
        const v4f h3 = *(const v4f*)(hb + 12);
        const v4f h4 = *(const v4f*)(hb + 16);
        const v4f h5 = *(const v4f*)(hb + 20);
        const v4f h6 = *(const v4f*)(hb + 24);
        const v4f h7 = *(const v4f*)(hb + 28);
        ff_head(TT - 1, h0, h1, h2, h3, h4, h5, h6, h7);
    }

    // ---- epilogue: normalize from LDS, write out ONCE, t-outer ----
    float mcv[NCLS], icv[NCLS];
    #pragma unroll
    for (int cc = 0; cc < NCLS; ++cc) {
        mcv[cc] = rl(mrun, cc);
        icv[cc] = 1.0f / rl(srun, cc);
    }
    #pragma unroll
    for (int i = 0; i < TT / 64; ++i) {
        const int tt = j + 64 * i;
        float* op = out + ((size_t)tt * BB + b) * NCLS;
        #pragma unroll
        for (int cc = 0; cc < NCLS; ++cc)
            op[cc] = __expf(shlg[tt][cc] - mcv[cc]) * icv[cc];
    }
}

// ---------------- round-2 verified fused kernel (fallback path) ----------------
template <bool TAB>
__global__ __launch_bounds__(64) void lstm_all(
    const int* __restrict__ x, const float* __restrict__ emb,
    const float* __restrict__ W_ih, const float* __restrict__ W_hh,
    const float* __restrict__ b_ih, const float* __restrict__ b_hh,
    const float* __restrict__ W1, const float* __restrict__ b1,
    const float* __restrict__ W2, const float* __restrict__ b2,
    const float2* __restrict__ tab, float* __restrict__ out)
{
    const int b  = blockIdx.x;
    const int j  = threadIdx.x;
    const int m  = j & 31;
    const bool lo = j < 32;
    const int rA = j, rB = j + 64;

    float whhA[HID], whhB[HID];
    #pragma unroll
    for (int k = 0; k < HID; k += 4) {
        float4 a;
        a = *(const float4*)(W_hh + rA * HID + k); whhA[k]=a.x; whhA[k+1]=a.y; whhA[k+2]=a.z; whhA[k+3]=a.w;
        a = *(const float4*)(W_hh + rB * HID + k); whhB[k]=a.x; whhB[k+1]=a.y; whhB[k+2]=a.z; whhB[k+3]=a.w;
    }
    float wihA[HID], wihB[HID];
    float biasA = 0.f, biasB = 0.f;
    if constexpr (!TAB) {
        #pragma unroll
        for (int k = 0; k < HID; k += 4) {
            float4 a;
            a = *(const float4*)(W_ih + rA * HID + k); wihA[k]=a.x; wihA[k+1]=a.y; wihA[k+2]=a.z; wihA[k+3]=a.w;
            a = *(const float4*)(W_ih + rB * HID + k); wihB[k]=a.x; wihB[k+1]=a.y; wihB[k+2]=a.z; wihB[k+3]=a.w;
        }
        biasA = b_ih[rA] + b_hh[rA];
        biasB = b_ih[rB] + b_hh[rB];
    }
    const int f16 = j & 15;
    float w1r[HID];
    #pragma unroll
    for (int k = 0; k < HID; ++k) w1r[k] = W1[f16 * HID + k];
    const int cls = j & 7;
    const int c7  = (cls < NCLS) ? cls : 0;
    float w2r[FFD];
    #pragma unroll
    for (int f = 0; f < FFD; ++f) w2r[f] = W2[c7 * FFD + f];
    const float b1v = b1[f16];
    const float b2v = b2[c7];

    float h = 0.f, c = 0.f;
    float mrun = -3.0e38f, srun = 0.f;

    auto gates = [&](float accA, float accB) {
        const float actA = sigf(accA);
        const float sB   = lo ? 2.0f * accB : accB;
        const float sgB  = sigf(sB);
        const float actB = lo ? 2.0f * sgB - 1.0f : sgB;
        const float oA = __shfl_xor(actA, 32);
        const float oB = __shfl_xor(actB, 32);
        const float gi = lo ? actA : oA;
        const float gf = lo ? oA   : actA;
        const float gg = lo ? actB : oB;
        const float go = lo ? oB   : actB;
        c = fmaf(gf, c, gi * gg);
        h = go * tanh_fast(c);
    };

    auto ff_head = [&](int t_out, const float* hsv) {
        float z0 = b1v, z1 = 0.f;
        #pragma unroll
        for (int k = 0; k < HID; k += 2) {
            z0 = fmaf(w1r[k],     hsv[k],     z0);
            z1 = fmaf(w1r[k + 1], hsv[k + 1], z1);
        }
        const float z = fmaxf(z0 + z1, 0.0f);
        float lgv = b2v;
        #pragma unroll
        for (int f = 0; f < FFD; ++f) lgv = fmaf(w2r[f], rl(z, f), lgv);
        const float mn = fmaxf(mrun, lgv);
        srun = fmaf(srun, __expf(mrun - mn), __expf(lgv - mn));
        mrun = mn;
        if (j < NCLS) out[(t_out * BB + b) * NCLS + j] = lgv;
    };

    int xvn1 = x[1 * BB + b];
    int xvn2 = x[2 * BB + b];
    float2 xg = make_float2(0.f, 0.f);
    float eA = 0.f;
    if constexpr (TAB) xg = tab[(size_t)x[b] * 64 + j];
    else               eA = emb[x[b] * EMB + m];

    if constexpr (TAB) {
        gates(xg.x, xg.y);
    } else {
        float es[EMB];
        #pragma unroll
        for (int k = 0; k < EMB; ++k) es[k] = rl(eA, k);
        float p0 = biasA, p1 = 0.f, q0 = biasB, q1 = 0.f;
        #pragma unroll
        for (int k = 0; k < EMB; k += 2) {
            p0 = fmaf(wihA[k],   es[k],   p0); p1 = fmaf(wihA[k+1], es[k+1], p1);
            q0 = fmaf(wihB[k],   es[k],   q0); q1 = fmaf(wihB[k+1], es[k+1], q1);
        }
        gates(p0 + p1, q0 + q1);
    }
    if constexpr (TAB) xg = tab[(size_t)xvn1 * 64 + j];
    else               eA = emb[xvn1 * EMB + m];
    xvn1 = xvn2;
    xvn2 = x[3 * BB + b];

    for (int t = 1; t < TT; ++t) {
        float2 xg_n = make_float2(0.f, 0.f);
        float  e_n  = 0.f;
        if (t + 1 < TT) {
            if constexpr (TAB) xg_n = tab[(size_t)xvn1 * 64 + j];
            else               e_n  = emb[xvn1 * EMB + m];
        }
        const int xv_n3 = (t + 3 < TT) ? x[(t + 3) * BB + b] : 0;

        float hsv[HID];
        #pragma unroll
        for (int k = 0; k < HID; ++k) hsv[k] = rl(h, k);

        ff_head(t - 1, hsv);

        float p0, p1 = 0.f, q0, q1 = 0.f;
        if constexpr (TAB) { p0 = xg.x; q0 = xg.y; }
        else               { p0 = biasA; q0 = biasB; }
        if constexpr (!TAB) {
            float es[EMB];
            #pragma unroll
            for (int k = 0; k < EMB; ++k) es[k] = rl(eA, k);
            #pragma unroll
            for (int k = 0; k < EMB; k += 2) {
                p0 = fmaf(wihA[k],   es[k],   p0); p1 = fmaf(wihA[k+1], es[k+1], p1);
                q0 = fmaf(wihB[k],   es[k],   q0); q1 = fmaf(wihB[k+1], es[k+1], q1);
            }
        }
        #pragma unroll
        for (int k = 0; k < HID; k += 2) {
            p0 = fmaf(whhA[k],   hsv[k],   p0); p1 = fmaf(whhA[k+1], hsv[k+1], p1);
            q0 = fmaf(whhB[k],   hsv[k],   q0); q1 = fmaf(whhB[k+1], hsv[k+1], q1);
        }
        gates(p0 + p1, q0 + q1);

        xg = xg_n; eA = e_n; xvn1 = xvn2; xvn2 = xv_n3;
    }

    {
        float hsv[HID];
        #pragma unroll
        for (int k = 0; k < HID; ++k) hsv[k] = rl(h, k);
        ff_head(TT - 1, hsv);
    }

    #pragma unroll 1
    for (int cc = 0; cc < NCLS; ++cc) {
        const float mc = rl(mrun, cc);
        const float sc = rl(srun, cc);
        const float ic = 1.0f / sc;
        #pragma unroll
        for (int i = 0; i < TT / 64; ++i) {
            const int t = j + 64 * i;
            const int a = (t * BB + b) * NCLS + cc;
            out[a] = __expf(out[a] - mc) * ic;
        }
    }
}

extern "C" void kernel_launch(void* const* d_in, const int* in_sizes, int n_in,
                              void* d_out, int out_size, void* d_ws, size_t ws_size,
                              hipStream_t stream) {
    const int*   x   = (const int*)  d_in[0];
    const float* emb = (const float*)d_in[1];
    const float* Wih = (const float*)d_in[2];
    const float* Whh = (const float*)d_in[3];
    const float* bih = (const float*)d_in[4];
    const float* bhh = (const float*)d_in[5];
    const float* W1  = (const float*)d_in[6];
    const float* b1  = (const float*)d_in[7];
    const float* W2  = (const float*)d_in[8];
    const float* b2  = (const float*)d_in[9];
    float* out = (float*)d_out;

    const size_t tab_bytes = (size_t)VOCABN * 128 * sizeof(float);   // 512 000
    if (ws_size >= tab_bytes) {
        float2* tab = (float2*)d_ws;
        build_xg<<<VOCABN, 64, 0, stream>>>(emb, Wih, bih, bhh, tab, 1);
        lstm_fused<<<BB, 64, 0, stream>>>(x, tab, Whh, W1, b1, W2, b2, out);
    } else {
        lstm_all<false><<<BB, 64, 0, stream>>>(x, emb, Wih, Whh, bih, bhh,
                                               W1, b1, W2, b2, nullptr, out);
    }
}

// Round 11
// 253.231 us; speedup vs baseline: 1.4827x; 1.1914x over previous
//
#include <hip/hip_runtime.h>
#include <math.h>

#define TT    512
#define BB    512
#define HID   32
#define EMB   32
#define FFD   16
#define NCLS  7
#define VOCABN 1000

typedef float v2f __attribute__((ext_vector_type(2)));
typedef float v4f __attribute__((ext_vector_type(4)));

#define NLOG2E  (-1.4426950408889634f)
#define N2LOG2E (-2.8853900817779268f)

__device__ __forceinline__ float rl(float v, int k) {
    return __int_as_float(__builtin_amdgcn_readlane(__float_as_int(v), k));
}
__device__ __forceinline__ float fast_rcp(float x) {
#if defined(__has_builtin)
#if __has_builtin(__builtin_amdgcn_rcpf)
    return __builtin_amdgcn_rcpf(x);
#else
    return 1.0f / x;
#endif
#else
    return 1.0f / x;
#endif
}
__device__ __forceinline__ float sigf(float x) { return fast_rcp(1.0f + __expf(-x)); }
__device__ __forceinline__ float tanh_fast(float x) { return 2.0f * sigf(2.0f * x) - 1.0f; }

__device__ __forceinline__ v2f fma2(v2f a, v2f b, v2f c) {
#if defined(__has_builtin)
#if __has_builtin(__builtin_elementwise_fma)
    return __builtin_elementwise_fma(a, b, c);
#else
    v2f r; r.x = fmaf(a.x, b.x, c.x); r.y = fmaf(a.y, b.y, c.y); return r;
#endif
#else
    v2f r; r.x = fmaf(a.x, b.x, c.x); r.y = fmaf(a.y, b.y, c.y); return r;
#endif
}

// Cross-half (lane ^ 32) exchange via v_permlane32_swap_b32 (VALU).
// Orientation-proof: r[0]^r[1]^self == partner.
__device__ __forceinline__ float xhalf_swap(float v) {
#if defined(__has_builtin)
#if __has_builtin(__builtin_amdgcn_permlane32_swap)
    const unsigned u = __float_as_uint(v);
    auto r = __builtin_amdgcn_permlane32_swap(u, u, false, false);
    return __uint_as_float((r[0] ^ r[1]) ^ u);
#else
    return __shfl_xor(v, 32);
#endif
#else
    return __shfl_xor(v, 32);
#endif
}

// xg_table[v][j] = {W_ih[j,:]·emb[v,:]+b[j], W_ih[j+64,:]·emb[v,:]+b[j+64]}
// scaled!=0: entries pre-multiplied by activation log2-scales (see lstm_fused).
__global__ __launch_bounds__(64) void build_xg(
    const float* __restrict__ emb, const float* __restrict__ W_ih,
    const float* __restrict__ b_ih, const float* __restrict__ b_hh,
    float2* __restrict__ tab, int scaled)
{
    const int v = blockIdx.x;
    const int j = threadIdx.x;
    const float* e  = emb + v * EMB;
    const float* w0 = W_ih + j * EMB;
    const float* w1 = W_ih + (j + 64) * EMB;
    float a0 = b_ih[j]      + b_hh[j];
    float a1 = b_ih[j + 64] + b_hh[j + 64];
    #pragma unroll
    for (int k = 0; k < EMB; ++k) {
        const float ek = e[k];
        a0 = fmaf(w0[k], ek, a0);
        a1 = fmaf(w1[k], ek, a1);
    }
    float s0 = 1.0f, s1 = 1.0f;
    if (scaled) { s0 = NLOG2E; s1 = (j < 32) ? N2LOG2E : NLOG2E; }
    tab[v * 64 + j] = make_float2(a0 * s0, a1 * s1);
}

// FULLY FUSED, v3. R10 EVIDENCE: fused FF with per-step readlane-logits +
// online-softmax cost +445 cyc/step - the SERIAL sub-chains (16-deep rl(z,f)
// fma chain, mrun/srun exp chain) stall the in-order wave; the WIDE part
// (16 independent pk_fma for z) is free. THIS version keeps only z in the
// loop (16 pk_fma + relu + 1 conflict-free LDS write, all off-chain) and
// moves logits/max/sum/normalize to a wave-parallel epilogue (lane handles
// 8 timesteps; W2/b2 are uniform s_loads; shfl_xor trees; out written once).
// shlg2 padded to 17 floats/row: write banks (t*17+f)%32 = 16 distinct,
// read banks (17j+f)%32 = 2-way over 64 lanes -> zero conflicts.
__global__ __launch_bounds__(64)
__attribute__((amdgpu_waves_per_eu(1, 1)))
void lstm_fused(
    const int* __restrict__ x, const float2* __restrict__ tab,
    const float* __restrict__ W_hh,
    const float* __restrict__ W1, const float* __restrict__ b1,
    const float* __restrict__ W2, const float* __restrict__ b2,
    float* __restrict__ out)
{
    const int b  = blockIdx.x;
    const int j  = threadIdx.x;
    const int m  = j & 31;
    const bool lo = j < 32;

    __shared__ __align__(16) float sh[8 * HID];     // h broadcast staging (1 KB)
    __shared__ __align__(16) float shlg2[TT][17];   // z [t][f], pad 17 (34.8 KB)

    // ---- W_hh rows j, j+64 -> 32 named v2f pairs, pre-scaled ----
    const float fA = NLOG2E;
    const float fB = lo ? N2LOG2E : NLOG2E;
    const v2f sA2 = {fA, fA};
    const v2f sB2 = {fB, fB};
    const v4f* WA = (const v4f*)(W_hh + j * HID);
    const v4f* WB = (const v4f*)(W_hh + (j + 64) * HID);
    v4f t;
    v2f wpa0,wpa1,wpa2,wpa3,wpa4,wpa5,wpa6,wpa7,wpa8,wpa9,wpa10,wpa11,wpa12,wpa13,wpa14,wpa15;
    v2f wpb0,wpb1,wpb2,wpb3,wpb4,wpb5,wpb6,wpb7,wpb8,wpb9,wpb10,wpb11,wpb12,wpb13,wpb14,wpb15;
    t = WA[0]; wpa0  = t.lo * sA2; wpa1  = t.hi * sA2;
    t = WA[1]; wpa2  = t.lo * sA2; wpa3  = t.hi * sA2;
    t = WA[2]; wpa4  = t.lo * sA2; wpa5  = t.hi * sA2;
    t = WA[3]; wpa6  = t.lo * sA2; wpa7  = t.hi * sA2;
    t = WA[4]; wpa8  = t.lo * sA2; wpa9  = t.hi * sA2;
    t = WA[5]; wpa10 = t.lo * sA2; wpa11 = t.hi * sA2;
    t = WA[6]; wpa12 = t.lo * sA2; wpa13 = t.hi * sA2;
    t = WA[7]; wpa14 = t.lo * sA2; wpa15 = t.hi * sA2;
    t = WB[0]; wpb0  = t.lo * sB2; wpb1  = t.hi * sB2;
    t = WB[1]; wpb2  = t.lo * sB2; wpb3  = t.hi * sB2;
    t = WB[2]; wpb4  = t.lo * sB2; wpb5  = t.hi * sB2;
    t = WB[3]; wpb6  = t.lo * sB2; wpb7  = t.hi * sB2;
    t = WB[4]; wpb8  = t.lo * sB2; wpb9  = t.hi * sB2;
    t = WB[5]; wpb10 = t.lo * sB2; wpb11 = t.hi * sB2;
    t = WB[6]; wpb12 = t.lo * sB2; wpb13 = t.hi * sB2;
    t = WB[7]; wpb14 = t.lo * sB2; wpb15 = t.hi * sB2;

    // ---- z weights: lane j computes z[f16] ----
    const int f16 = j & 15;
    v2f w1p0,w1p1,w1p2,w1p3,w1p4,w1p5,w1p6,w1p7,w1p8,w1p9,w1p10,w1p11,w1p12,w1p13,w1p14,w1p15;
    {
        const v4f* W1r = (const v4f*)(W1 + f16 * HID);
        v4f q;
        q = W1r[0]; w1p0  = q.lo; w1p1  = q.hi;
        q = W1r[1]; w1p2  = q.lo; w1p3  = q.hi;
        q = W1r[2]; w1p4  = q.lo; w1p5  = q.hi;
        q = W1r[3]; w1p6  = q.lo; w1p7  = q.hi;
        q = W1r[4]; w1p8  = q.lo; w1p9  = q.hi;
        q = W1r[5]; w1p10 = q.lo; w1p11 = q.hi;
        q = W1r[6]; w1p12 = q.lo; w1p13 = q.hi;
        q = W1r[7]; w1p14 = q.lo; w1p15 = q.hi;
    }
    const float b1v = b1[f16];

    float h = 0.f, c = 0.f;

    // z for step t_out from the broadcast quads of h_{t_out}; LDS store only.
    // 16 independent pk_fma (2 chains of 8) + relu: rides the broadcast gap.
    auto z_store = [&](int t_out, v4f h0, v4f h1, v4f h2, v4f h3,
                                  v4f h4, v4f h5, v4f h6, v4f h7) {
        v2f z0 = {b1v, 0.f}, z1 = {0.f, 0.f};
        z0 = fma2(w1p0,  h0.lo, z0);  z1 = fma2(w1p1,  h0.hi, z1);
        z0 = fma2(w1p2,  h1.lo, z0);  z1 = fma2(w1p3,  h1.hi, z1);
        z0 = fma2(w1p4,  h2.lo, z0);  z1 = fma2(w1p5,  h2.hi, z1);
        z0 = fma2(w1p6,  h3.lo, z0);  z1 = fma2(w1p7,  h3.hi, z1);
        z0 = fma2(w1p8,  h4.lo, z0);  z1 = fma2(w1p9,  h4.hi, z1);
        z0 = fma2(w1p10, h5.lo, z0);  z1 = fma2(w1p11, h5.hi, z1);
        z0 = fma2(w1p12, h6.lo, z0);  z1 = fma2(w1p13, h6.hi, z1);
        z0 = fma2(w1p14, h7.lo, z0);  z1 = fma2(w1p15, h7.hi, z1);
        const v2f zs = z0 + z1;
        const float z = fmaxf(zs.x + zs.y, 0.0f);
        if (j < 16) shlg2[t_out][j] = z;   // banks (t*17+f)%32: conflict-free
    };

    // broadcast source slot 7 = "previous h"; zero for t=0
    if (lo) sh[7 * HID + m] = 0.0f;

    // ---- prologue: block-0 xg in registers, block-1 indices staged ----
    int xiB[8];
    float2 cxg[8];
    {
        int xi0[8];
        #pragma unroll
        for (int u = 0; u < 8; ++u) xi0[u] = x[u * BB + b];
        #pragma unroll
        for (int u = 0; u < 8; ++u) xiB[u] = x[(8 + u) * BB + b];
        #pragma unroll
        for (int u = 0; u < 8; ++u) cxg[u] = tab[(size_t)xi0[u] * 64 + j];
    }

    for (int t8 = 0; t8 < TT / 8; ++t8) {
        // next-block gathers + next-next-block index loads up front;
        // consumed after the 8 serial steps below -> latency fully hidden.
        float2 nxg[8];
        #pragma unroll
        for (int u = 0; u < 8; ++u) nxg[u] = tab[(size_t)xiB[u] * 64 + j];
        int xiN[8];
        const int nb2 = (t8 + 2 < TT / 8) ? (t8 + 2) * 8 : 0;  // tail: dead but safe
        #pragma unroll
        for (int u = 0; u < 8; ++u) xiN[u] = x[(nb2 + u) * BB + b];

        #pragma unroll
        for (int u = 0; u < 8; ++u) {
            // broadcast: previous step's h lives in sh slot (u-1)&7.
            // Uniform-address ds_read_b128 -> all lanes get the same quad.
            const float* hb = sh + ((u + 7) & 7) * HID;
            const v4f h0 = *(const v4f*)(hb + 0);
            const v4f h1 = *(const v4f*)(hb + 4);
            const v4f h2 = *(const v4f*)(hb + 8);
            const v4f h3 = *(const v4f*)(hb + 12);
            const v4f h4 = *(const v4f*)(hb + 16);
            const v4f h5 = *(const v4f*)(hb + 20);
            const v4f h6 = *(const v4f*)(hb + 24);
            const v4f h7 = *(const v4f*)(hb + 28);

            // dot: 32 pk_fma in 4 independent chains of depth 8
            v2f aP0 = {cxg[u].x, 0.f}, aP1 = {0.f, 0.f};
            v2f aQ0 = {cxg[u].y, 0.f}, aQ1 = {0.f, 0.f};
            aP0 = fma2(wpa0,  h0.lo, aP0);  aP1 = fma2(wpa1,  h0.hi, aP1);
            aQ0 = fma2(wpb0,  h0.lo, aQ0);  aQ1 = fma2(wpb1,  h0.hi, aQ1);
            aP0 = fma2(wpa2,  h1.lo, aP0);  aP1 = fma2(wpa3,  h1.hi, aP1);
            aQ0 = fma2(wpb2,  h1.lo, aQ0);  aQ1 = fma2(wpb3,  h1.hi, aQ1);
            aP0 = fma2(wpa4,  h2.lo, aP0);  aP1 = fma2(wpa5,  h2.hi, aP1);
            aQ0 = fma2(wpb4,  h2.lo, aQ0);  aQ1 = fma2(wpb5,  h2.hi, aQ1);
            aP0 = fma2(wpa6,  h3.lo, aP0);  aP1 = fma2(wpa7,  h3.hi, aP1);
            aQ0 = fma2(wpb6,  h3.lo, aQ0);  aQ1 = fma2(wpb7,  h3.hi, aQ1);
            aP0 = fma2(wpa8,  h4.lo, aP0);  aP1 = fma2(wpa9,  h4.hi, aP1);
            aQ0 = fma2(wpb8,  h4.lo, aQ0);  aQ1 = fma2(wpb9,  h4.hi, aQ1);
            aP0 = fma2(wpa10, h5.lo, aP0);  aP1 = fma2(wpa11, h5.hi, aP1);
            aQ0 = fma2(wpb10, h5.lo, aQ0);  aQ1 = fma2(wpb11, h5.hi, aQ1);
            aP0 = fma2(wpa12, h6.lo, aP0);  aP1 = fma2(wpa13, h6.hi, aP1);
            aQ0 = fma2(wpb12, h6.lo, aQ0);  aQ1 = fma2(wpb13, h6.hi, aQ1);
            aP0 = fma2(wpa14, h7.lo, aP0);  aP1 = fma2(wpa15, h7.hi, aP1);
            aQ0 = fma2(wpb14, h7.lo, aQ0);  aQ1 = fma2(wpb15, h7.hi, aQ1);
            const v2f aP = aP0 + aP1;
            const v2f aQ = aQ0 + aQ1;
            const float accA = aP.x + aP.y;   // pre-scaled by -log2e
            const float accB = aQ.x + aQ.y;   // pre-scaled (-2log2e g / -log2e o)

            // sigmoid/tanh in exp2 form (scales folded into acc)
            const float actA = fast_rcp(1.0f + __builtin_exp2f(accA)); // i (lo) / f (hi)
            const float sgB  = fast_rcp(1.0f + __builtin_exp2f(accB));
            const float actB = lo ? fmaf(2.0f, sgB, -1.0f) : sgB;      // g (lo) / o (hi)
            const float oA = xhalf_swap(actA);
            const float oB = xhalf_swap(actB);
            const float gi = lo ? actA : oA;
            const float gf = lo ? oA   : actA;
            const float gg = lo ? actB : oB;
            const float go = lo ? oB   : actB;
            c = fmaf(gf, c, gi * gg);
            const float tc = fmaf(2.0f,
                fast_rcp(1.0f + __builtin_exp2f(c * N2LOG2E)), -1.0f); // tanh(c)
            h = go * tc;

            if (lo) sh[u * HID + m] = h;   // staging write == next-step broadcast src

            // z for t-1 (wide, independent; fills the write->read gap)
            if (t8 + u > 0)
                z_store(t8 * 8 + u - 1, h0, h1, h2, h3, h4, h5, h6, h7);
        }

        // rotate double buffers
        #pragma unroll
        for (int u = 0; u < 8; ++u) { cxg[u] = nxg[u]; xiB[u] = xiN[u]; }
    }

    // final z for t = TT-1 (h_511 sits in slot 7)
    {
        const float* hb = sh + 7 * HID;
        const v4f h0 = *(const v4f*)(hb + 0);
        const v4f h1 = *(const v4f*)(hb + 4);
        const v4f h2 = *(const v4f*)(hb + 8);
        const v4f h3 = *(const v4f*)(hb + 12);
        const v4f h4 = *(const v4f*)(hb + 16);
        const v4f h5 = *(const v4f*)(hb + 20);
        const v4f h6 = *(const v4f*)(hb + 24);
        const v4f h7 = *(const v4f*)(hb + 28);
        z_store(TT - 1, h0, h1, h2, h3, h4, h5, h6, h7);
    }

    // ---- wave-parallel epilogue: logits, softmax-over-t, single out write.
    // Lane j handles t = j + 64i (i=0..7). W2/b2 uniform -> s_loads.
    float lg[8][NCLS];
    #pragma unroll
    for (int i = 0; i < 8; ++i) {
        const int tt = j + 64 * i;
        float zz[FFD];
        #pragma unroll
        for (int f = 0; f < FFD; ++f) zz[f] = shlg2[tt][f];
        #pragma unroll
        for (int cc = 0; cc < NCLS; ++cc) {
            float a0 = b2[cc], a1 = 0.f, a2 = 0.f, a3 = 0.f;
            #pragma unroll
            for (int f = 0; f < FFD; f += 4) {
                a0 = fmaf(W2[cc * FFD + f],     zz[f],     a0);
                a1 = fmaf(W2[cc * FFD + f + 1], zz[f + 1], a1);
                a2 = fmaf(W2[cc * FFD + f + 2], zz[f + 2], a2);
                a3 = fmaf(W2[cc * FFD + f + 3], zz[f + 3], a3);
            }
            lg[i][cc] = (a0 + a1) + (a2 + a3);
        }
    }
    #pragma unroll
    for (int cc = 0; cc < NCLS; ++cc) {
        float mm = lg[0][cc];
        #pragma unroll
        for (int i = 1; i < 8; ++i) mm = fmaxf(mm, lg[i][cc]);
        #pragma unroll
        for (int off = 32; off; off >>= 1) mm = fmaxf(mm, __shfl_xor(mm, off));
        float ss = 0.f;
        #pragma unroll
        for (int i = 0; i < 8; ++i) { lg[i][cc] = __expf(lg[i][cc] - mm); ss += lg[i][cc]; }
        #pragma unroll
        for (int off = 32; off; off >>= 1) ss += __shfl_xor(ss, off);
        const float ic = fast_rcp(ss);
        #pragma unroll
        for (int i = 0; i < 8; ++i) lg[i][cc] *= ic;
    }
    #pragma unroll
    for (int i = 0; i < 8; ++i) {
        const int tt = j + 64 * i;
        float* op = out + ((size_t)tt * BB + b) * NCLS;
        #pragma unroll
        for (int cc = 0; cc < NCLS; ++cc) op[cc] = lg[i][cc];
    }
}

// ---------------- round-2 verified fused kernel (fallback path) ----------------
template <bool TAB>
__global__ __launch_bounds__(64) void lstm_all(
    const int* __restrict__ x, const float* __restrict__ emb,
    const float* __restrict__ W_ih, const float* __restrict__ W_hh,
    const float* __restrict__ b_ih, const float* __restrict__ b_hh,
    const float* __restrict__ W1, const float* __restrict__ b1,
    const float* __restrict__ W2, const float* __restrict__ b2,
    const float2* __restrict__ tab, float* __restrict__ out)
{
    const int b  = blockIdx.x;
    const int j  = threadIdx.x;
    const int m  = j & 31;
    const bool lo = j < 32;
    const int rA = j, rB = j + 64;

    float whhA[HID], whhB[HID];
    #pragma unroll
    for (int k = 0; k < HID; k += 4) {
        float4 a;
        a = *(const float4*)(W_hh + rA * HID + k); whhA[k]=a.x; whhA[k+1]=a.y; whhA[k+2]=a.z; whhA[k+3]=a.w;
        a = *(const float4*)(W_hh + rB * HID + k); whhB[k]=a.x; whhB[k+1]=a.y; whhB[k+2]=a.z; whhB[k+3]=a.w;
    }
    float wihA[HID], wihB[HID];
    float biasA = 0.f, biasB = 0.f;
    if constexpr (!TAB) {
        #pragma unroll
        for (int k = 0; k < HID; k += 4) {
            float4 a;
            a = *(const float4*)(W_ih + rA * HID + k); wihA[k]=a.x; wihA[k+1]=a.y; wihA[k+2]=a.z; wihA[k+3]=a.w;
            a = *(const float4*)(W_ih + rB * HID + k); wihB[k]=a.x; wihB[k+1]=a.y; wihB[k+2]=a.z; wihB[k+3]=a.w;
        }
        biasA = b_ih[rA] + b_hh[rA];
        biasB = b_ih[rB] + b_hh[rB];
    }
    const int f16 = j & 15;
    float w1r[HID];
    #pragma unroll
    for (int k = 0; k < HID; ++k) w1r[k] = W1[f16 * HID + k];
    const int cls = j & 7;
    const int c7  = (cls < NCLS) ? cls : 0;
    float w2r[FFD];
    #pragma unroll
    for (int f = 0; f < FFD; ++f) w2r[f] = W2[c7 * FFD + f];
    const float b1v = b1[f16];
    const float b2v = b2[c7];

    float h = 0.f, c = 0.f;
    float mrun = -3.0e38f, srun = 0.f;

    auto gates = [&](float accA, float accB) {
        const float actA = sigf(accA);
        const float sB   = lo ? 2.0f * accB : accB;
        const float sgB  = sigf(sB);
        const float actB = lo ? 2.0f * sgB - 1.0f : sgB;
        const float oA = __shfl_xor(actA, 32);
        const float oB = __shfl_xor(actB, 32);
        const float gi = lo ? actA : oA;
        const float gf = lo ? oA   : actA;
        const float gg = lo ? actB : oB;
        const float go = lo ? oB   : actB;
        c = fmaf(gf, c, gi * gg);
        h = go * tanh_fast(c);
    };

    auto ff_head = [&](int t_out, const float* hsv) {
        float z0 = b1v, z1 = 0.f;
        #pragma unroll
        for (int k = 0; k < HID; k += 2) {
            z0 = fmaf(w1r[k],     hsv[k],     z0);
            z1 = fmaf(w1r[k + 1], hsv[k + 1], z1);
        }
        const float z = fmaxf(z0 + z1, 0.0f);
        float lgv = b2v;
        #pragma unroll
        for (int f = 0; f < FFD; ++f) lgv = fmaf(w2r[f], rl(z, f), lgv);
        const float mn = fmaxf(mrun, lgv);
        srun = fmaf(srun, __expf(mrun - mn), __expf(lgv - mn));
        mrun = mn;
        if (j < NCLS) out[(t_out * BB + b) * NCLS + j] = lgv;
    };

    int xvn1 = x[1 * BB + b];
    int xvn2 = x[2 * BB + b];
    float2 xg = make_float2(0.f, 0.f);
    float eA = 0.f;
    if constexpr (TAB) xg = tab[(size_t)x[b] * 64 + j];
    else               eA = emb[x[b] * EMB + m];

    if constexpr (TAB) {
        gates(xg.x, xg.y);
    } else {
        float es[EMB];
        #pragma unroll
        for (int k = 0; k < EMB; ++k) es[k] = rl(eA, k);
        float p0 = biasA, p1 = 0.f, q0 = biasB, q1 = 0.f;
        #pragma unroll
        for (int k = 0; k < EMB; k += 2) {
            p0 = fmaf(wihA[k],   es[k],   p0); p1 = fmaf(wihA[k+1], es[k+1], p1);
            q0 = fmaf(wihB[k],   es[k],   q0); q1 = fmaf(wihB[k+1], es[k+1], q1);
        }
        gates(p0 + p1, q0 + q1);
    }
    if constexpr (TAB) xg = tab[(size_t)xvn1 * 64 + j];
    else               eA = emb[xvn1 * EMB + m];
    xvn1 = xvn2;
    xvn2 = x[3 * BB + b];

    for (int t = 1; t < TT; ++t) {
        float2 xg_n = make_float2(0.f, 0.f);
        float  e_n  = 0.f;
        if (t + 1 < TT) {
            if constexpr (TAB) xg_n = tab[(size_t)xvn1 * 64 + j];
            else               e_n  = emb[xvn1 * EMB + m];
        }
        const int xv_n3 = (t + 3 < TT) ? x[(t + 3) * BB + b] : 0;

        float hsv[HID];
        #pragma unroll
        for (int k = 0; k < HID; ++k) hsv[k] = rl(h, k);

        ff_head(t - 1, hsv);

        float p0, p1 = 0.f, q0, q1 = 0.f;
        if constexpr (TAB) { p0 = xg.x; q0 = xg.y; }
        else               { p0 = biasA; q0 = biasB; }
        if constexpr (!TAB) {
            float es[EMB];
            #pragma unroll
            for (int k = 0; k < EMB; ++k) es[k] = rl(eA, k);
            #pragma unroll
            for (int k = 0; k < EMB; k += 2) {
                p0 = fmaf(wihA[k],   es[k],   p0); p1 = fmaf(wihA[k+1], es[k+1], p1);
                q0 = fmaf(wihB[k],   es[k],   q0); q1 = fmaf(wihB[k+1], es[k+1], q1);
            }
        }
        #pragma unroll
        for (int k = 0; k < HID; k += 2) {
            p0 = fmaf(whhA[k],   hsv[k],   p0); p1 = fmaf(whhA[k+1], hsv[k+1], p1);
            q0 = fmaf(whhB[k],   hsv[k],   q0); q1 = fmaf(whhB[k+1], hsv[k+1], q1);
        }
        gates(p0 + p1, q0 + q1);

        xg = xg_n; eA = e_n; xvn1 = xvn2; xvn2 = xv_n3;
    }

    {
        float hsv[HID];
        #pragma unroll
        for (int k = 0; k < HID; ++k) hsv[k] = rl(h, k);
        ff_head(TT - 1, hsv);
    }

    #pragma unroll 1
    for (int cc = 0; cc < NCLS; ++cc) {
        const float mc = rl(mrun, cc);
        const float sc = rl(srun, cc);
        const float ic = 1.0f / sc;
        #pragma unroll
        for (int i = 0; i < TT / 64; ++i) {
            const int t = j + 64 * i;
            const int a = (t * BB + b) * NCLS + cc;
            out[a] = __expf(out[a] - mc) * ic;
        }
    }
}

extern "C" void kernel_launch(void* const* d_in, const int* in_sizes, int n_in,
                              void* d_out, int out_size, void* d_ws, size_t ws_size,
                              hipStream_t stream) {
    const int*   x   = (const int*)  d_in[0];
    const float* emb = (const float*)d_in[1];
    const float* Wih = (const float*)d_in[2];
    const float* Whh = (const float*)d_in[3];
    const float* bih = (const float*)d_in[4];
    const float* bhh = (const float*)d_in[5];
    const float* W1  = (const float*)d_in[6];
    const float* b1  = (const float*)d_in[7];
    const float* W2  = (const float*)d_in[8];
    const float* b2  = (const float*)d_in[9];
    float* out = (float*)d_out;

    const size_t tab_bytes = (size_t)VOCABN * 128 * sizeof(float);   // 512 000
    if (ws_size >= tab_bytes) {
        float2* tab = (float2*)d_ws;
        build_xg<<<VOCABN, 64, 0, stream>>>(emb, Wih, bih, bhh, tab, 1);
        lstm_fused<<<BB, 64, 0, stream>>>(x, tab, Whh, W1, b1, W2, b2, out);
    } else {
        lstm_all<false><<<BB, 64, 0, stream>>>(x, emb, Wih, Whh, bih, bhh,
                                               W1, b1, W2, b2, nullptr, out);
    }
}